// Round 1
// baseline (351.458 us; speedup 1.0000x reference)
//
#include <hip/hip_runtime.h>
#include <hip/hip_bf16.h>

#define HIDDEN 768
#define NH 12
#define HD 64
#define BB 4
#define SS 2048
#define M_TOT (BB * SS)      // 8192
#define NQKV (3 * HIDDEN)    // 2304

typedef __attribute__((ext_vector_type(8))) short bf16x8;
typedef __attribute__((ext_vector_type(4))) float f32x4;

__device__ inline unsigned short f2bf(float x) {
    __hip_bfloat16 h = __float2bfloat16(x);
    return *reinterpret_cast<unsigned short*>(&h);
}

// ---------------------------------------------------------------------------
// Kernel 1: cast hidden_states and Wq|Wk|Wv to bf16 workspace buffers.
// a_bf: [8192][768] bf16 ; w_bf: [2304][768] bf16 (rows 0-767 Wq, 768-1535 Wk,
// 1536-2303 Wv). Each thread converts 4 floats.
// ---------------------------------------------------------------------------
__global__ __launch_bounds__(256) void cast_kernel(
    const float* __restrict__ hs, const float* __restrict__ wq,
    const float* __restrict__ wk, const float* __restrict__ wv,
    unsigned short* __restrict__ a_bf, unsigned short* __restrict__ w_bf) {
    const int HS_N = M_TOT * HIDDEN / 4;   // 1,572,864
    const int W_N = HIDDEN * HIDDEN / 4;   // 147,456
    int idx = blockIdx.x * blockDim.x + threadIdx.x;
    if (idx >= HS_N + 3 * W_N) return;
    if (idx < HS_N) {
        float4 v = ((const float4*)hs)[idx];
        ushort4 o;
        o.x = f2bf(v.x); o.y = f2bf(v.y); o.z = f2bf(v.z); o.w = f2bf(v.w);
        ((ushort4*)a_bf)[idx] = o;
    } else {
        int widx = idx - HS_N;
        const float* src;
        int off;
        if (widx < W_N)        { src = wq; off = widx; }
        else if (widx < 2*W_N) { src = wk; off = widx - W_N; }
        else                   { src = wv; off = widx - 2 * W_N; }
        float4 v = ((const float4*)src)[off];
        ushort4 o;
        o.x = f2bf(v.x); o.y = f2bf(v.y); o.z = f2bf(v.z); o.w = f2bf(v.w);
        ((ushort4*)w_bf)[widx] = o;
    }
}

// ---------------------------------------------------------------------------
// Kernel 2: QKV projection GEMM. C[m][n] = sum_k A[m][k]*W[n][k] + bias[n].
// M=8192, N=2304, K=768. 128x128 tile, 4 waves (2x2), BK=32,
// mfma_f32_16x16x32_bf16. Output bf16 [8192][2304].
// ---------------------------------------------------------------------------
__global__ __launch_bounds__(256) void qkv_gemm(
    const unsigned short* __restrict__ A, const unsigned short* __restrict__ W,
    const float* __restrict__ bq, const float* __restrict__ bk,
    const float* __restrict__ bv, unsigned short* __restrict__ C) {
    __shared__ unsigned short As[128][40];   // pitch 40 bf16 = 80B (16B-aligned rows)
    __shared__ unsigned short Bs[128][40];
    const int tid = threadIdx.x;
    const int m0 = blockIdx.y * 128;
    const int n0 = blockIdx.x * 128;
    const int w = tid >> 6, l = tid & 63;
    const int wm = w >> 1, wn = w & 1;
    const int lrow = l & 15;
    const int lk = (l >> 4) * 8;
    const int srow = tid >> 2;        // 0..63
    const int skk = (tid & 3) * 8;    // 0,8,16,24

    f32x4 acc[4][4] = {};

    for (int k0 = 0; k0 < HIDDEN; k0 += 32) {
        __syncthreads();
        bf16x8 a0 = *(const bf16x8*)(A + (size_t)(m0 + srow) * HIDDEN + k0 + skk);
        bf16x8 a1 = *(const bf16x8*)(A + (size_t)(m0 + srow + 64) * HIDDEN + k0 + skk);
        bf16x8 b0 = *(const bf16x8*)(W + (size_t)(n0 + srow) * HIDDEN + k0 + skk);
        bf16x8 b1 = *(const bf16x8*)(W + (size_t)(n0 + srow + 64) * HIDDEN + k0 + skk);
        *(bf16x8*)&As[srow][skk] = a0;
        *(bf16x8*)&As[srow + 64][skk] = a1;
        *(bf16x8*)&Bs[srow][skk] = b0;
        *(bf16x8*)&Bs[srow + 64][skk] = b1;
        __syncthreads();
        bf16x8 af[4], bfr[4];
#pragma unroll
        for (int mi = 0; mi < 4; mi++)
            af[mi] = *(const bf16x8*)&As[wm * 64 + mi * 16 + lrow][lk];
#pragma unroll
        for (int ni = 0; ni < 4; ni++)
            bfr[ni] = *(const bf16x8*)&Bs[wn * 64 + ni * 16 + lrow][lk];
#pragma unroll
        for (int mi = 0; mi < 4; mi++)
#pragma unroll
            for (int ni = 0; ni < 4; ni++)
                acc[mi][ni] = __builtin_amdgcn_mfma_f32_16x16x32_bf16(
                    af[mi], bfr[ni], acc[mi][ni], 0, 0, 0);
    }

#pragma unroll
    for (int mi = 0; mi < 4; mi++) {
#pragma unroll
        for (int ni = 0; ni < 4; ni++) {
            int col = n0 + wn * 64 + ni * 16 + lrow;
            float bias = col < 768 ? bq[col]
                       : (col < 1536 ? bk[col - 768] : bv[col - 1536]);
#pragma unroll
            for (int i = 0; i < 4; i++) {
                int row = m0 + wm * 64 + mi * 16 + (l >> 4) * 4 + i;
                C[(size_t)row * NQKV + col] = f2bf(acc[mi][ni][i] + bias);
            }
        }
    }
}

// ---------------------------------------------------------------------------
// Kernel 3: flash attention with ALiBi + padding mask.
// Block: 64 q rows of one (b,h). 4 waves x 16 q-rows. KVBLK=64.
// QKV layout: [8192][2304] bf16, Q at col h*64, K at 768+h*64, V at 1536+h*64.
// Output f32 [B,S,768].
// ---------------------------------------------------------------------------
__global__ __launch_bounds__(256) void attn_kernel(
    const unsigned short* __restrict__ QKV, const int* __restrict__ mask,
    float* __restrict__ out) {
    __shared__ unsigned short Vt[64][88];      // V^T: [d][kv], pitch 88
    __shared__ unsigned short Pl[4][16][88];   // per-wave P: [q][kv], pitch 88
    const int tid = threadIdx.x;
    const int w = tid >> 6, l = tid & 63;
    const int qt = blockIdx.x;   // 0..31
    const int bh = blockIdx.y;   // 0..47
    const int b = bh / NH, h = bh % NH;
    const int lrow = l & 15;
    const int g = l >> 4;
    const int lk = g * 8;

    const float slope = (h < 8) ? exp2f(-(float)(h + 1))
                                : exp2f(-((float)(h - 8) + 0.5f));
    const float scaling = 0.125f;  // 64^-0.5
    const int s0 = qt * 64;
    const int qrow_w = s0 + w * 16;
    const size_t rowbase = (size_t)b * SS * NQKV;

    // Q fragments (held for whole kernel)
    bf16x8 qf[2];
    {
        const unsigned short* qptr =
            QKV + rowbase + (size_t)(qrow_w + lrow) * NQKV + h * HD;
        qf[0] = *(const bf16x8*)(qptr + lk);
        qf[1] = *(const bf16x8*)(qptr + 32 + lk);
    }

    f32x4 acc_o[4] = {};
    float m_run[4], l_run[4];
#pragma unroll
    for (int i = 0; i < 4; i++) { m_run[i] = -1e30f; l_run[i] = 0.f; }

    for (int kt = 0; kt < SS / 64; kt++) {
        const int kv0 = kt * 64;
        __syncthreads();  // prior PV reads of Vt done
        // stage V^T into LDS: thread handles rows tid/8 (+32), 8 cols
        {
            int r = tid >> 3;
            int c = (tid & 7) * 8;
#pragma unroll
            for (int rr = 0; rr < 2; rr++) {
                int row = r + rr * 32;
                bf16x8 v = *(const bf16x8*)(QKV + rowbase +
                                            (size_t)(kv0 + row) * NQKV + 1536 +
                                            h * HD + c);
#pragma unroll
                for (int j = 0; j < 8; j++)
                    Vt[c + j][row] = (unsigned short)v[j];
            }
        }
        __syncthreads();  // Vt ready

        // QK^T: 16 q x 64 kv per wave, K frags straight from global (L2-hot)
        f32x4 sacc[4];
        const unsigned short* kbase = QKV + rowbase + 768 + h * HD;
#pragma unroll
        for (int nf = 0; nf < 4; nf++) {
            const unsigned short* kptr =
                kbase + (size_t)(kv0 + nf * 16 + lrow) * NQKV;
            bf16x8 k0 = *(const bf16x8*)(kptr + lk);
            bf16x8 k1 = *(const bf16x8*)(kptr + 32 + lk);
            f32x4 z = {};
            z = __builtin_amdgcn_mfma_f32_16x16x32_bf16(qf[0], k0, z, 0, 0, 0);
            z = __builtin_amdgcn_mfma_f32_16x16x32_bf16(qf[1], k1, z, 0, 0, 0);
            sacc[nf] = z;
        }

        // online softmax (rows: q = qrow_w + g*4 + i ; cols: kv0 + nf*16 + lrow)
        float p[4][4];
        float mt[4];
#pragma unroll
        for (int i = 0; i < 4; i++) mt[i] = -1e30f;
#pragma unroll
        for (int nf = 0; nf < 4; nf++) {
            int kv = kv0 + nf * 16 + lrow;
            float mb = mask[b * SS + kv] ? 0.f : -1e30f;
#pragma unroll
            for (int i = 0; i < 4; i++) {
                int q = qrow_w + g * 4 + i;
                float sv = sacc[nf][i] * scaling -
                           slope * fabsf((float)(kv - q)) + mb;
                p[nf][i] = sv;
                mt[i] = fmaxf(mt[i], sv);
            }
        }
#pragma unroll
        for (int i = 0; i < 4; i++) {
            float v = mt[i];
            v = fmaxf(v, __shfl_xor(v, 1));
            v = fmaxf(v, __shfl_xor(v, 2));
            v = fmaxf(v, __shfl_xor(v, 4));
            v = fmaxf(v, __shfl_xor(v, 8));
            mt[i] = v;
        }
        float corr[4], lt[4];
#pragma unroll
        for (int i = 0; i < 4; i++) {
            float mn = fmaxf(m_run[i], mt[i]);
            corr[i] = __expf(m_run[i] - mn);
            m_run[i] = mn;
            lt[i] = 0.f;
        }
#pragma unroll
        for (int nf = 0; nf < 4; nf++)
#pragma unroll
            for (int i = 0; i < 4; i++) {
                float e = __expf(p[nf][i] - m_run[i]);
                p[nf][i] = e;
                lt[i] += e;
            }
#pragma unroll
        for (int i = 0; i < 4; i++) {
            float v = lt[i];
            v += __shfl_xor(v, 1);
            v += __shfl_xor(v, 2);
            v += __shfl_xor(v, 4);
            v += __shfl_xor(v, 8);
            l_run[i] = l_run[i] * corr[i] + v;
#pragma unroll
            for (int nf = 0; nf < 4; nf++) acc_o[nf][i] *= corr[i];
        }
        // write P (bf16) to per-wave LDS for transpose to A-fragment layout
#pragma unroll
        for (int nf = 0; nf < 4; nf++)
#pragma unroll
            for (int i = 0; i < 4; i++)
                Pl[w][g * 4 + i][nf * 16 + lrow] = f2bf(p[nf][i]);
        __syncthreads();  // P visible (and keeps Vt stable)

        // PV: acc_o[nf] += P[16x64] @ V[64x(nf*16..)]
        bf16x8 pf0 = *(const bf16x8*)&Pl[w][lrow][lk];
        bf16x8 pf1 = *(const bf16x8*)&Pl[w][lrow][32 + lk];
#pragma unroll
        for (int nf = 0; nf < 4; nf++) {
            bf16x8 v0 = *(const bf16x8*)&Vt[nf * 16 + lrow][lk];
            bf16x8 v1 = *(const bf16x8*)&Vt[nf * 16 + lrow][32 + lk];
            acc_o[nf] = __builtin_amdgcn_mfma_f32_16x16x32_bf16(
                pf0, v0, acc_o[nf], 0, 0, 0);
            acc_o[nf] = __builtin_amdgcn_mfma_f32_16x16x32_bf16(
                pf1, v1, acc_o[nf], 0, 0, 0);
        }
    }

    // epilogue: normalize and store f32
#pragma unroll
    for (int i = 0; i < 4; i++) {
        float inv = 1.0f / l_run[i];
        int q = qrow_w + g * 4 + i;
        float* optr = out + (size_t)(b * SS + q) * HIDDEN + h * HD;
#pragma unroll
        for (int nf = 0; nf < 4; nf++)
            optr[nf * 16 + lrow] = acc_o[nf][i] * inv;
    }
}

// ---------------------------------------------------------------------------
extern "C" void kernel_launch(void* const* d_in, const int* in_sizes, int n_in,
                              void* d_out, int out_size, void* d_ws,
                              size_t ws_size, hipStream_t stream) {
    const float* hs = (const float*)d_in[0];
    const float* wq = (const float*)d_in[1];
    const float* bq = (const float*)d_in[2];
    const float* wk = (const float*)d_in[3];
    const float* bk = (const float*)d_in[4];
    const float* wv = (const float*)d_in[5];
    const float* bv = (const float*)d_in[6];
    const int* mask = (const int*)d_in[7];
    float* out = (float*)d_out;

    unsigned short* a_bf = (unsigned short*)d_ws;                    // 12.6 MB
    unsigned short* w_bf = a_bf + (size_t)M_TOT * HIDDEN;            // 3.5 MB
    unsigned short* qkv = w_bf + (size_t)NQKV * HIDDEN;              // 37.7 MB

    int castN = (M_TOT * HIDDEN + 3 * HIDDEN * HIDDEN) / 4;  // 2,015,232
    cast_kernel<<<(castN + 255) / 256, 256, 0, stream>>>(hs, wq, wk, wv, a_bf,
                                                         w_bf);

    dim3 ggrid(NQKV / 128, M_TOT / 128);  // (18, 64)
    qkv_gemm<<<ggrid, 256, 0, stream>>>(a_bf, w_bf, bq, bk, bv, qkv);

    dim3 agrid(SS / 64, BB * NH);  // (32, 48)
    attn_kernel<<<agrid, 256, 0, stream>>>(qkv, mask, out);
}